// Round 11
// baseline (121.048 us; speedup 1.0000x reference)
//
#include <hip/hip_runtime.h>

namespace {
constexpr int HIN = 130, WIN = 130;
constexpr int HH = 128, WW = 128;
constexpr int C = 128, CR = 32, B = 8;
constexpr int CHW = HIN * WIN;   // 16900

// Transpose W_reduce (32x128) -> WredT (128x32): the unrolled r-loop then
// reads contiguous uniform floats (compiler scalarizes to s_load_dwordx*).
__global__ void transpose_wred(const float* __restrict__ Wred, float* __restrict__ WredT) {
    int idx = blockIdx.x * 256 + threadIdx.x;   // 4096 elements
    int r = idx >> 7;
    int c = idx & 127;
    WredT[c * CR + r] = Wred[r * C + c];
}

// lgkm-only workgroup barrier: leaves global loads (vmcnt) in flight.
__device__ __forceinline__ void lgkm_barrier() {
    asm volatile("s_waitcnt lgkmcnt(0)\n\ts_barrier" ::: "memory");
    __builtin_amdgcn_sched_barrier(0);
}

// Block = 256 threads = 4 waves x 64 lanes; one full output row, 2 adjacent
// pixels per thread. Wave q owns groups {2q,2q+1}, channels [32q,32q+32).
// R11: register-level software pipelining (R10 was stall-bound in stage 3:
// 12 loads / 36 FMA per iter at VGPR=64 left nothing in flight).
__global__ __launch_bounds__(256, 4) void invol_direct(
    const float* __restrict__ x,      // [B][C][130][130]
    const float* __restrict__ WredT,  // [128][32]
    const float* __restrict__ bred,   // [32]
    const float* __restrict__ Wkern,  // [72][32]
    const float* __restrict__ bkern,  // [72]
    float* __restrict__ out)          // [B][C][128][128]
{
    __shared__ float red2[CR][128];   // [r][pixel], b64 access, 16 KB

    const int t = threadIdx.x;
    const int p = t & 63;
    const int q = __builtin_amdgcn_readfirstlane(t >> 6);

    // XCD-chunked swizzle: h-adjacent blocks (sharing 2/3 tap rows) land on
    // the same XCD L2. 1024 % 8 == 0 -> bijective.
    const int orig = blockIdx.x;
    const int blk  = (orig & 7) * 128 + (orig >> 3);
    const int b    = blk >> 7;
    const int h    = blk & (HH - 1);

    const float* xb = x + (size_t)b * C * CHW;

    // ================= stage 1: red[8q..8q+8) for pixels 2p,2p+1 =========
    // 8 chunks of 16 channels, double-buffered: chunk c+1's 32 loads issue
    // during chunk c's 256 FMAs.
    const float* xc = xb + (size_t)(h + 1) * WIN + (2 * p + 1);
    float r0[8], r1[8];
#pragma unroll
    for (int r = 0; r < 8; ++r) { r0[r] = bred[q * 8 + r]; r1[r] = r0[r]; }

    float A0[16], A1[16], B0[16], B1[16];

    auto ld1 = [&](float (&v0)[16], float (&v1)[16], int cb) {
#pragma unroll
        for (int cc = 0; cc < 16; ++cc) {
            const float* cp = xc + (size_t)(cb * 16 + cc) * CHW;
            v0[cc] = cp[0];
            v1[cc] = cp[1];
        }
    };
    auto fma1 = [&](const float (&v0)[16], const float (&v1)[16], int cb) {
#pragma unroll
        for (int cc = 0; cc < 16; ++cc) {
#pragma unroll
            for (int r = 0; r < 8; ++r) {
                float wgt = WredT[(cb * 16 + cc) * CR + q * 8 + r];   // uniform -> s_load
                r0[r] = fmaf(wgt, v0[cc], r0[r]);
                r1[r] = fmaf(wgt, v1[cc], r1[r]);
            }
        }
    };

    ld1(A0, A1, 0);
#pragma unroll
    for (int cb = 0; cb < 8; ++cb) {
        if ((cb & 1) == 0) {
            if (cb < 7) ld1(B0, B1, cb + 1);
            fma1(A0, A1, cb);
        } else {
            if (cb < 7) ld1(A0, A1, cb + 1);
            fma1(B0, B1, cb);
        }
    }
#pragma unroll
    for (int r = 0; r < 8; ++r)
        *(float2*)&red2[q * 8 + r][2 * p] = make_float2(r0[r], r1[r]);

    // ====== stage 3 tap pipeline (starts before the barrier) =============
    const float* xrow = xb + (size_t)h * WIN + 2 * p;
    float* op = out + (((size_t)(b * C + 32 * q)) * HH + h) * WW + 2 * p;

    float2 TA[24], TB[24];   // 4 channels x 3 rows x {cols 2p..2p+1, 2p+2..2p+3}

    auto ldc = [&](float2 (&T)[24], int c0) {   // channels 32q+c0 .. +c0+3
#pragma unroll
        for (int m = 0; m < 4; ++m) {
            const float* xp = xrow + (size_t)(32 * q + c0 + m) * CHW;
#pragma unroll
            for (int i = 0; i < 3; ++i) {
                T[6 * m + 2 * i]     = *(const float2*)(xp + i * WIN);
                T[6 * m + 2 * i + 1] = *(const float2*)(xp + i * WIN + 2);
            }
        }
    };
    float kh0[9], kh1[9];
    auto kernhalf = [&](int half) {   // kern slice for group 2q+half, both px
#pragma unroll
        for (int k = 0; k < 9; ++k) { kh0[k] = bkern[18 * q + 9 * half + k]; kh1[k] = kh0[k]; }
#pragma unroll
        for (int r = 0; r < CR; ++r) {
            float2 rv = *(const float2*)&red2[r][2 * p];
#pragma unroll
            for (int k = 0; k < 9; ++k) {
                float wgt = Wkern[(18 * q + 9 * half + k) * CR + r];   // uniform
                kh0[k] = fmaf(wgt, rv.x, kh0[k]);
                kh1[k] = fmaf(wgt, rv.y, kh1[k]);
            }
        }
    };
    auto fmac = [&](const float2 (&T)[24], int c0) {
#pragma unroll
        for (int m = 0; m < 4; ++m) {
            float a0 = 0.f, a1 = 0.f;
#pragma unroll
            for (int i = 0; i < 3; ++i) {
                float2 ta = T[6 * m + 2 * i];
                float2 tb = T[6 * m + 2 * i + 1];
                a0 = fmaf(kh0[3 * i + 0], ta.x, a0);
                a0 = fmaf(kh0[3 * i + 1], ta.y, a0);
                a0 = fmaf(kh0[3 * i + 2], tb.x, a0);
                a1 = fmaf(kh1[3 * i + 0], ta.y, a1);
                a1 = fmaf(kh1[3 * i + 1], tb.x, a1);
                a1 = fmaf(kh1[3 * i + 2], tb.y, a1);
            }
            *(float2*)(op + (size_t)(c0 + m) * HH * WW) = make_float2(a0, a1);
        }
    };

    ldc(TA, 0);        // chunk-0 taps in flight across the barrier,
    lgkm_barrier();    // hidden under stage-2's FMAs (no vmcnt drain)

    // ========== stage 2 + 3 interleaved, fully unrolled pipeline =========
    kernhalf(0);
    ldc(TB, 4);  fmac(TA, 0);
    ldc(TA, 8);  fmac(TB, 4);
    ldc(TB, 12); fmac(TA, 8);
    ldc(TA, 16); fmac(TB, 12);   // TA gets half-1's first chunk early
    kernhalf(1);                 // loads in flight during kern compute
    ldc(TB, 20); fmac(TA, 16);
    ldc(TA, 24); fmac(TB, 20);
    ldc(TB, 28); fmac(TA, 24);
    fmac(TB, 28);
}
} // namespace

extern "C" void kernel_launch(void* const* d_in, const int* in_sizes, int n_in,
                              void* d_out, int out_size, void* d_ws, size_t ws_size,
                              hipStream_t stream) {
    const float* x     = (const float*)d_in[0];
    const float* Wred  = (const float*)d_in[1];
    const float* bred  = (const float*)d_in[2];
    const float* Wkern = (const float*)d_in[3];
    const float* bkern = (const float*)d_in[4];
    float* out   = (float*)d_out;
    float* WredT = (float*)d_ws;   // 16 KB scratch

    transpose_wred<<<16, 256, 0, stream>>>(Wred, WredT);

    // 8 b * 128 h = 1024 blocks, one full output row each
    invol_direct<<<1024, 256, 0, stream>>>(x, WredT, bred, Wkern, bkern, out);
}

// Round 12
// 74.548 us; speedup vs baseline: 1.6238x; 1.6238x over previous
//
#include <hip/hip_runtime.h>

namespace {
constexpr int HIN = 130, WIN = 130;
constexpr int HH = 128, WW = 128;
constexpr int C = 128, CR = 32, B = 8;
constexpr int CHW = HIN * WIN;   // 16900

// Transpose W_reduce (32x128) -> WredT (128x32): the unrolled r-loop then
// reads contiguous uniform floats (compiler scalarizes to s_load_dwordx*).
__global__ void transpose_wred(const float* __restrict__ Wred, float* __restrict__ WredT) {
    int idx = blockIdx.x * 256 + threadIdx.x;   // 4096 elements
    int r = idx >> 7;
    int c = idx & 127;
    WredT[c * CR + r] = Wred[r * C + c];
}

// lgkm-only workgroup barrier: leaves global loads (vmcnt) in flight.
__device__ __forceinline__ void lgkm_barrier() {
    asm volatile("s_waitcnt lgkmcnt(0)\n\ts_barrier" ::: "memory");
    __builtin_amdgcn_sched_barrier(0);
}

// Block = 256 threads = 4 waves x 64 lanes; one full output row, 2 adjacent
// pixels per thread. Wave q owns groups {2q,2q+1}, channels [32q,32q+32).
// R12: stage-3 software pipeline sized to the register budget. R11's
// 2x24-float2 buffers + stage-1 seam exceeded the 128-reg cap and spilled
// (WRITE_SIZE 65->207 MB). Now: 3 x 12-float2 buffers (72 regs), 2-channel
// chunks, prefetch distance 2 -> peak live ~108 regs.
__global__ __launch_bounds__(256, 4) void invol_direct(
    const float* __restrict__ x,      // [B][C][130][130]
    const float* __restrict__ WredT,  // [128][32]
    const float* __restrict__ bred,   // [32]
    const float* __restrict__ Wkern,  // [72][32]
    const float* __restrict__ bkern,  // [72]
    float* __restrict__ out)          // [B][C][128][128]
{
    __shared__ float red2[CR][128];   // [r][pixel], b64 access, 16 KB

    const int t = threadIdx.x;
    const int p = t & 63;
    const int q = __builtin_amdgcn_readfirstlane(t >> 6);

    // XCD-chunked swizzle: h-adjacent blocks (sharing 2/3 tap rows) land on
    // the same XCD L2. 1024 % 8 == 0 -> bijective.
    const int orig = blockIdx.x;
    const int blk  = (orig & 7) * 128 + (orig >> 3);
    const int b    = blk >> 7;
    const int h    = blk & (HH - 1);

    const float* xb = x + (size_t)b * C * CHW;

    // ======== stage 1: red[8q..8q+8) for pixels 2p,2p+1 (R10 form) =======
    const float* xc = xb + (size_t)(h + 1) * WIN + (2 * p + 1);
    float r0[8], r1[8];
#pragma unroll
    for (int r = 0; r < 8; ++r) { r0[r] = bred[q * 8 + r]; r1[r] = r0[r]; }

#pragma unroll
    for (int cb = 0; cb < 4; ++cb) {
        float xv0[32], xv1[32];
#pragma unroll
        for (int cc = 0; cc < 32; ++cc) {
            const float* cp = xc + (size_t)(cb * 32 + cc) * CHW;
            xv0[cc] = cp[0];
            xv1[cc] = cp[1];
        }
#pragma unroll
        for (int cc = 0; cc < 32; ++cc) {
#pragma unroll
            for (int r = 0; r < 8; ++r) {
                float wgt = WredT[(cb * 32 + cc) * CR + q * 8 + r];   // uniform
                r0[r] = fmaf(wgt, xv0[cc], r0[r]);
                r1[r] = fmaf(wgt, xv1[cc], r1[r]);
            }
        }
    }
#pragma unroll
    for (int r = 0; r < 8; ++r)
        *(float2*)&red2[q * 8 + r][2 * p] = make_float2(r0[r], r1[r]);

    // ======== stage 3 pipeline machinery ================================
    const float* xrow = xb + (size_t)h * WIN + 2 * p;
    float* op = out + (((size_t)(b * C + 32 * q)) * HH + h) * WW + 2 * p;

    float2 T0[12], T1[12], T2[12];   // chunk = 2 channels x 3 rows x 2 b64

    auto ldc = [&](float2 (&T)[12], int j) {   // chunk j: channels 32q+2j,+2j+1
#pragma unroll
        for (int m = 0; m < 2; ++m) {
            const float* xp = xrow + (size_t)(32 * q + 2 * j + m) * CHW;
#pragma unroll
            for (int i = 0; i < 3; ++i) {
                T[6 * m + 2 * i]     = *(const float2*)(xp + i * WIN);
                T[6 * m + 2 * i + 1] = *(const float2*)(xp + i * WIN + 2);
            }
        }
    };
    float khA[9], khB[9];   // kern slice for current half, pixels 0/1
    auto kernhalf = [&](int half) {
#pragma unroll
        for (int k = 0; k < 9; ++k) { khA[k] = bkern[18 * q + 9 * half + k]; khB[k] = khA[k]; }
#pragma unroll
        for (int r = 0; r < CR; ++r) {
            float2 rv = *(const float2*)&red2[r][2 * p];
#pragma unroll
            for (int k = 0; k < 9; ++k) {
                float wgt = Wkern[(18 * q + 9 * half + k) * CR + r];   // uniform
                khA[k] = fmaf(wgt, rv.x, khA[k]);
                khB[k] = fmaf(wgt, rv.y, khB[k]);
            }
        }
    };
    auto fmac = [&](const float2 (&T)[12], int j) {
#pragma unroll
        for (int m = 0; m < 2; ++m) {
            float a0 = 0.f, a1 = 0.f;
#pragma unroll
            for (int i = 0; i < 3; ++i) {
                float2 ta = T[6 * m + 2 * i];
                float2 tb = T[6 * m + 2 * i + 1];
                a0 = fmaf(khA[3 * i + 0], ta.x, a0);
                a0 = fmaf(khA[3 * i + 1], ta.y, a0);
                a0 = fmaf(khA[3 * i + 2], tb.x, a0);
                a1 = fmaf(khB[3 * i + 0], ta.y, a1);
                a1 = fmaf(khB[3 * i + 1], tb.x, a1);
                a1 = fmaf(khB[3 * i + 2], tb.y, a1);
            }
            *(float2*)(op + (size_t)(2 * j + m) * HH * WW) = make_float2(a0, a1);
        }
    };

    // chunks 0,1 in flight across the barrier, hidden under kernhalf(0)
    ldc(T0, 0); ldc(T1, 1);
    lgkm_barrier();
    kernhalf(0);

    // 16 chunks, buffer rotation j%3, prefetch distance 2
    ldc(T2, 2);   fmac(T0, 0);
    ldc(T0, 3);   fmac(T1, 1);
    ldc(T1, 4);   fmac(T2, 2);
    ldc(T2, 5);   fmac(T0, 3);
    ldc(T0, 6);   fmac(T1, 4);
    ldc(T1, 7);   fmac(T2, 5);
    ldc(T2, 8);   fmac(T0, 6);
    ldc(T0, 9);   fmac(T1, 7);
    kernhalf(1);                    // chunks 8,9 already in flight
    ldc(T1, 10);  fmac(T2, 8);
    ldc(T2, 11);  fmac(T0, 9);
    ldc(T0, 12);  fmac(T1, 10);
    ldc(T1, 13);  fmac(T2, 11);
    ldc(T2, 14);  fmac(T0, 12);
    ldc(T0, 15);  fmac(T1, 13);
    fmac(T2, 14);
    fmac(T0, 15);
}
} // namespace

extern "C" void kernel_launch(void* const* d_in, const int* in_sizes, int n_in,
                              void* d_out, int out_size, void* d_ws, size_t ws_size,
                              hipStream_t stream) {
    const float* x     = (const float*)d_in[0];
    const float* Wred  = (const float*)d_in[1];
    const float* bred  = (const float*)d_in[2];
    const float* Wkern = (const float*)d_in[3];
    const float* bkern = (const float*)d_in[4];
    float* out   = (float*)d_out;
    float* WredT = (float*)d_ws;   // 16 KB scratch

    transpose_wred<<<16, 256, 0, stream>>>(Wred, WredT);

    // 8 b * 128 h = 1024 blocks, one full output row each
    invol_direct<<<1024, 256, 0, stream>>>(x, WredT, bred, Wkern, bkern, out);
}